// Round 4
// baseline (442.597 us; speedup 1.0000x reference)
//
#include <hip/hip_runtime.h>
#include <hip/hip_bf16.h>
#include <stdint.h>

#define DEVINL __device__ __forceinline__

typedef __attribute__((ext_vector_type(4))) float f32x4;
typedef __attribute__((ext_vector_type(8))) __bf16 bfv8;
typedef __attribute__((ext_vector_type(8))) short s16x8;
typedef __attribute__((ext_vector_type(4))) short s16x4;

// ---- helpers ----
DEVINL short f2bf(float f) {  // fp32 -> bf16 bits, RTNE
  union { float f; unsigned u; } v; v.f = f;
  unsigned r = v.u + 0x7FFFu + ((v.u >> 16) & 1u);
  return (short)(r >> 16);
}
DEVINL float bf2f(short h) {
  union { unsigned u; float f; } v; v.u = ((unsigned)(unsigned short)h) << 16;
  return v.f;
}
// bijective XCD swizzle (n % 8 == 0): dispatch slot p -> contiguous chunk per XCD
DEVINL int xswz(int p, int n) { return (p & 7) * (n >> 3) + (p >> 3); }

// ================= flatmm core: 128x128 block, 4 waves (2M x 2N), NO LDS =================
// Wave tile 64x64 = 4x4 frags of 16x16x32. Fragments loaded DIRECTLY global->VGPR:
// lane reads A[row = tile + mi*16 + (l&15)][k0 + (l>>4)*8 .. +8] — 16B contiguous, the exact
// MFMA A/B fragment layout (same mapping the verified LDS core used). 2-deep register
// double-buffer; no barriers -> compiler inserts counted vmcnt between refill and use.
template <bool REFILL>
DEVINL void step16(f32x4 (&acc)[4][4], bfv8 (&As)[4], bfv8 (&Bs)[4],
                   const short* const (&pa)[4], const short* const (&pb)[4], int koff) {
#pragma unroll
  for (int mi = 0; mi < 4; ++mi) {
#pragma unroll
    for (int nf = 0; nf < 4; ++nf)
      acc[mi][nf] = __builtin_amdgcn_mfma_f32_16x16x32_bf16(As[mi], Bs[nf], acc[mi][nf], 0, 0, 0);
    if (REFILL) As[mi] = *(const bfv8*)(pa[mi] + koff * 32);  // a-set[mi] dead after its row
  }
  if (REFILL) {
#pragma unroll
    for (int nf = 0; nf < 4; ++nf) Bs[nf] = *(const bfv8*)(pb[nf] + koff * 32);
  }
}

DEVINL void flat_core(const short* __restrict__ Ag, const short* __restrict__ Bg,
                      int lda, int ldb, int m0, int n0, int nkt, f32x4 (&acc)[4][4]) {
  const int l = threadIdx.x & 63, w = threadIdx.x >> 6;
  const int wm = w >> 1, wn = w & 1;
  const int lr = l & 15, lg = l >> 4;
  const short* pa[4];
  const short* pb[4];
#pragma unroll
  for (int i = 0; i < 4; ++i) {
    pa[i] = Ag + (size_t)(m0 + wm * 64 + i * 16 + lr) * lda + lg * 8;
    pb[i] = Bg + (size_t)(n0 + wn * 64 + i * 16 + lr) * ldb + lg * 8;
  }
  bfv8 a0[4], b0[4], a1[4], b1[4];
#pragma unroll
  for (int i = 0; i < 4; ++i) { a0[i] = *(const bfv8*)(pa[i]); b0[i] = *(const bfv8*)(pb[i]); }
#pragma unroll
  for (int i = 0; i < 4; ++i) { a1[i] = *(const bfv8*)(pa[i] + 32); b1[i] = *(const bfv8*)(pb[i] + 32); }
  int kt = 0;
#pragma unroll 1
  for (; kt + 4 <= nkt; kt += 2) {
    step16<true>(acc, a0, b0, pa, pb, kt + 2);
    step16<true>(acc, a1, b1, pa, pb, kt + 3);
  }
  step16<false>(acc, a0, b0, pa, pb, 0);
  step16<false>(acc, a1, b1, pa, pb, 0);
}

// ============ prep: cast fp32->bf16 (Q,V) fused with W transpose+cast ============
__global__ __launch_bounds__(256) void prep_kernel(
    const float* __restrict__ q, const float* __restrict__ v,
    const float* __restrict__ Wq, const float* __restrict__ Wk, const float* __restrict__ Wv,
    short* __restrict__ Qc, short* __restrict__ Vc,
    short* __restrict__ WTq, short* __restrict__ WTk, short* __restrict__ WTv) {
  __shared__ float tile[64][65];
  const int bx = blockIdx.x;
  if (bx < 8192) {
    const float* src = (bx < 4096) ? q : v;
    short* dst = (bx < 4096) ? Qc : Vc;
    const size_t i = ((size_t)(bx & 4095) * 256 + threadIdx.x) * 8;
    f32x4 x0 = *(const f32x4*)(src + i);
    f32x4 x1 = *(const f32x4*)(src + i + 4);
    s16x8 o;
#pragma unroll
    for (int j = 0; j < 4; ++j) { o[j] = f2bf(x0[j]); o[4 + j] = f2bf(x1[j]); }
    *(s16x8*)(dst + i) = o;
  } else {
    const int z = (bx - 8192) >> 8, xx = (bx - 8192) & 255;
    const float* W = (z == 0) ? Wq : (z == 1) ? Wk : Wv;
    short* WT = (z == 0) ? WTq : (z == 1) ? WTk : WTv;
    const int k0 = (xx & 15) << 6, n0 = (xx >> 4) << 6;
    const int c = threadIdx.x & 63, r0 = threadIdx.x >> 6;
#pragma unroll
    for (int i = 0; i < 16; ++i) {
      int r = (i << 2) + r0;
      tile[r][c] = W[(size_t)(k0 + r) * 1024 + n0 + c];
    }
    __syncthreads();
#pragma unroll
    for (int i = 0; i < 16; ++i) {
      int a = (i << 2) + r0;
      WT[(size_t)(n0 + a) * 1024 + k0 + c] = f2bf(tile[c][a]);
    }
  }
}

// ============ Q+K projections: 1024 blocks (sel x 64 bm x 8 bn) ============
__global__ __launch_bounds__(256, 2) void qkproj_kernel(
    const short* __restrict__ Qc, const short* __restrict__ Vc,
    const short* __restrict__ WTq, const short* __restrict__ WTk,
    const float* __restrict__ bq, const float* __restrict__ bk,
    short* __restrict__ Qb, short* __restrict__ Kb) {
  const int o = xswz(blockIdx.x, 1024);
  const int sel = o >> 9, r = o & 511;
  const int bm = r >> 3, bn = r & 7;
  const short* A = sel ? Vc : Qc;
  const short* BT = sel ? WTk : WTq;
  const float* bias = sel ? bk : bq;
  short* O = sel ? Kb : Qb;
  const int m0 = bm * 128, n0 = bn * 128;
  f32x4 acc[4][4];
#pragma unroll
  for (int i = 0; i < 4; ++i)
#pragma unroll
    for (int j = 0; j < 4; ++j) acc[i][j] = (f32x4){0.f, 0.f, 0.f, 0.f};
  flat_core(A, BT, 1024, 1024, m0, n0, 32, acc);
  const int l = threadIdx.x & 63, w = threadIdx.x >> 6;
  const int wm = w >> 1, wn = w & 1, lr = l & 15, lg = l >> 4;
#pragma unroll
  for (int mi = 0; mi < 4; ++mi) {
    const int row0 = m0 + wm * 64 + mi * 16 + lg * 4;
#pragma unroll
    for (int nf = 0; nf < 4; ++nf) {
      const int col = n0 + wn * 64 + nf * 16 + lr;
      const float bb = bias[col];
#pragma unroll
      for (int j = 0; j < 4; ++j)
        O[(size_t)(row0 + j) * 1024 + col] = f2bf(acc[mi][nf][j] + bb);
    }
  }
}

// ============ V projection -> VT[b][u][t]: 512 blocks (64 bm x 8 bn) ============
__global__ __launch_bounds__(256, 2) void vproj_kernel(
    const short* __restrict__ Vc, const short* __restrict__ WTv,
    const float* __restrict__ bv, short* __restrict__ VT) {
  __shared__ short lt[128 * 136];  // 34 KB transpose buffer
  const int o = xswz(blockIdx.x, 512);
  const int bm = o >> 3, bn = o & 7;
  const int m0 = bm * 128, n0 = bn * 128;  // m = t rows, n = u cols
  f32x4 acc[4][4];
#pragma unroll
  for (int i = 0; i < 4; ++i)
#pragma unroll
    for (int j = 0; j < 4; ++j) acc[i][j] = (f32x4){0.f, 0.f, 0.f, 0.f};
  flat_core(Vc, WTv, 1024, 1024, m0, n0, 32, acc);
  const int tid = threadIdx.x;
  const int l = tid & 63, w = tid >> 6;
  const int wm = w >> 1, wn = w & 1, lr = l & 15, lg = l >> 4;
  // acc -> LDS [u_local][t_local] (stride 136), bias added here
#pragma unroll
  for (int mi = 0; mi < 4; ++mi) {
    const int tl = wm * 64 + mi * 16 + lg * 4;
#pragma unroll
    for (int nf = 0; nf < 4; ++nf) {
      const int ul = wn * 64 + nf * 16 + lr;
      const float bb = bv[n0 + ul];
      s16x4 pk;
#pragma unroll
      for (int j = 0; j < 4; ++j) pk[j] = f2bf(acc[mi][nf][j] + bb);
      *(s16x4*)&lt[ul * 136 + tl] = pk;
    }
  }
  __syncthreads();
  const int b = m0 >> 11, t0 = m0 & 2047;
#pragma unroll
  for (int it = 0; it < 8; ++it) {
    const int cid = it * 256 + tid;
    const int u = cid >> 4, tc = cid & 15;
    s16x8 v8 = *(const s16x8*)&lt[u * 136 + tc * 8];
    *(s16x8*)(VT + ((size_t)b * 1024 + n0 + u) * 2048 + t0 + tc * 8) = v8;
  }
}

// ============ QK^T: scores = (Q.K)/32, bf16 out; 1024 blocks (4 bt x 16 bm x 16 bn) ============
__global__ __launch_bounds__(256, 2) void qkt_kernel(const short* __restrict__ Qb,
                                                     const short* __restrict__ Kb,
                                                     short* __restrict__ Sb) {
  const int o = xswz(blockIdx.x, 1024);
  const int bt = o >> 8, r = o & 255;
  const int bm = r >> 4, bn = r & 15;
  const short* A = Qb + (size_t)bt * 2097152;
  const short* B = Kb + (size_t)bt * 2097152;
  short* O = Sb + (size_t)bt * 4194304;
  const int m0 = bm * 128, n0 = bn * 128;
  f32x4 acc[4][4];
#pragma unroll
  for (int i = 0; i < 4; ++i)
#pragma unroll
    for (int j = 0; j < 4; ++j) acc[i][j] = (f32x4){0.f, 0.f, 0.f, 0.f};
  flat_core(A, B, 1024, 1024, m0, n0, 32, acc);
  const int l = threadIdx.x & 63, w = threadIdx.x >> 6;
  const int wm = w >> 1, wn = w & 1, lr = l & 15, lg = l >> 4;
#pragma unroll
  for (int mi = 0; mi < 4; ++mi) {
    const int row0 = m0 + wm * 64 + mi * 16 + lg * 4;
#pragma unroll
    for (int nf = 0; nf < 4; ++nf) {
      const int col = n0 + wn * 64 + nf * 16 + lr;
#pragma unroll
      for (int j = 0; j < 4; ++j)
        O[(size_t)(row0 + j) * 2048 + col] = f2bf(acc[mi][nf][j] * 0.03125f);
    }
  }
}

// ============ PV: out = P @ V (V via VT[b][u][t]), fp32; 512 blocks (4 bt x 16 bm x 8 bn) ============
__global__ __launch_bounds__(256, 2) void pv_kernel(const short* __restrict__ Sb,
                                                    const short* __restrict__ VT,
                                                    float* __restrict__ Out) {
  const int o = xswz(blockIdx.x, 512);
  const int bt = o >> 7, r = o & 127;
  const int bm = r >> 3, bn = r & 7;
  const short* A = Sb + (size_t)bt * 4194304;
  const short* B = VT + (size_t)bt * 2097152;
  float* O = Out + (size_t)bt * 2097152;
  const int m0 = bm * 128, n0 = bn * 128;
  f32x4 acc[4][4];
#pragma unroll
  for (int i = 0; i < 4; ++i)
#pragma unroll
    for (int j = 0; j < 4; ++j) acc[i][j] = (f32x4){0.f, 0.f, 0.f, 0.f};
  flat_core(A, B, 2048, 2048, m0, n0, 64, acc);
  const int l = threadIdx.x & 63, w = threadIdx.x >> 6;
  const int wm = w >> 1, wn = w & 1, lr = l & 15, lg = l >> 4;
#pragma unroll
  for (int mi = 0; mi < 4; ++mi) {
    const int row0 = m0 + wm * 64 + mi * 16 + lg * 4;
#pragma unroll
    for (int nf = 0; nf < 4; ++nf) {
      const int col = n0 + wn * 64 + nf * 16 + lr;
#pragma unroll
      for (int j = 0; j < 4; ++j)
        O[(size_t)(row0 + j) * 1024 + col] = acc[mi][nf][j];
    }
  }
}

// ============ Row softmax, in-place on bf16 scores [B*S rows][2048] ============
__global__ __launch_bounds__(256) void softmax_kernel(short* __restrict__ Sb) {
  const size_t row = blockIdx.x;
  short* p = Sb + row * 2048;
  const int tid = threadIdx.x;
  const int w = tid >> 6, l = tid & 63;
  s16x8 v = *(const s16x8*)(p + tid * 8);
  float f[8];
#pragma unroll
  for (int j = 0; j < 8; ++j) f[j] = bf2f(v[j]);
  float m = f[0];
#pragma unroll
  for (int j = 1; j < 8; ++j) m = fmaxf(m, f[j]);
#pragma unroll
  for (int o = 32; o > 0; o >>= 1) m = fmaxf(m, __shfl_xor(m, o, 64));
  __shared__ float redm[4], reds[4];
  if (l == 0) redm[w] = m;
  __syncthreads();
  m = fmaxf(fmaxf(redm[0], redm[1]), fmaxf(redm[2], redm[3]));
  float s = 0.f;
#pragma unroll
  for (int j = 0; j < 8; ++j) { f[j] = __expf(f[j] - m); s += f[j]; }
#pragma unroll
  for (int o = 32; o > 0; o >>= 1) s += __shfl_xor(s, o, 64);
  if (l == 0) reds[w] = s;
  __syncthreads();
  s = reds[0] + reds[1] + reds[2] + reds[3];
  const float inv = 1.f / s;
  s16x8 o8;
#pragma unroll
  for (int j = 0; j < 8; ++j) o8[j] = f2bf(f[j] * inv);
  *(s16x8*)(p + tid * 8) = o8;
}

// ============ launch ============
extern "C" void kernel_launch(void* const* d_in, const int* in_sizes, int n_in,
                              void* d_out, int out_size, void* d_ws, size_t ws_size,
                              hipStream_t stream) {
  const float* query = (const float*)d_in[0];
  const float* value = (const float*)d_in[1];
  const float* Wq = (const float*)d_in[2];
  const float* bq = (const float*)d_in[3];
  const float* Wk = (const float*)d_in[4];
  const float* bk = (const float*)d_in[5];
  const float* Wv = (const float*)d_in[6];
  const float* bv = (const float*)d_in[7];

  // Workspace layout (86 MB total):
  //  0: WTq(2M) 2M: WTk(2M) 4M: WTv(2M)
  //  6M: region X (32MB): Qc@6M(16M), Vc@22M(16M) [projection inputs];
  //      later reused as Sb@6M(32MB) [scores/P] -- lifetimes disjoint (stream-ordered)
  //  38M: Qb(16M)  54M: Kb(16M)  70M: VT(16M)
  char* ws = (char*)d_ws;
  short* WTq = (short*)(ws);
  short* WTk = (short*)(ws + ((size_t)2 << 20));
  short* WTv = (short*)(ws + ((size_t)4 << 20));
  short* Qc  = (short*)(ws + ((size_t)6 << 20));
  short* Vc  = (short*)(ws + ((size_t)22 << 20));
  short* Sb  = (short*)(ws + ((size_t)6 << 20));
  short* Qb  = (short*)(ws + ((size_t)38 << 20));
  short* Kb  = (short*)(ws + ((size_t)54 << 20));
  short* VT  = (short*)(ws + ((size_t)70 << 20));

  prep_kernel<<<dim3(8960), 256, 0, stream>>>(query, value, Wq, Wk, Wv, Qc, Vc, WTq, WTk, WTv);

  qkproj_kernel<<<dim3(1024), 256, 0, stream>>>(Qc, Vc, WTq, WTk, bq, bk, Qb, Kb);
  vproj_kernel<<<dim3(512), 256, 0, stream>>>(Vc, WTv, bv, VT);

  // scores[b][s][t] = (Q.K)/32
  qkt_kernel<<<dim3(1024), 256, 0, stream>>>(Qb, Kb, Sb);

  softmax_kernel<<<dim3(8192), 256, 0, stream>>>(Sb);

  // out[b][s][u] = P @ V
  pv_kernel<<<dim3(512), 256, 0, stream>>>(Sb, VT, (float*)d_out);
}

// Round 6
// 192.989 us; speedup vs baseline: 2.2934x; 2.2934x over previous
//
#include <hip/hip_runtime.h>
#include <hip/hip_bf16.h>
#include <stdint.h>

#define DEVINL __device__ __forceinline__

typedef __attribute__((ext_vector_type(4))) float f32x4;
typedef __attribute__((ext_vector_type(8))) __bf16 bfv8;
typedef __attribute__((ext_vector_type(8))) short s16x8;
typedef __attribute__((ext_vector_type(4))) short s16x4;

// ---- helpers ----
DEVINL short f2bf(float f) {  // fp32 -> bf16 bits, RTNE
  union { float f; unsigned u; } v; v.f = f;
  unsigned r = v.u + 0x7FFFu + ((v.u >> 16) & 1u);
  return (short)(r >> 16);
}
DEVINL float bf2f(short h) {
  union { unsigned u; float f; } v; v.u = ((unsigned)(unsigned short)h) << 16;
  return v.f;
}
DEVINL void gload_lds16(const void* g, void* l) {
  // 16B direct global->LDS. LDS dest = wave-uniform base + lane*16.
  __builtin_amdgcn_global_load_lds((__attribute__((address_space(1))) unsigned*)(g),
                                   (__attribute__((address_space(3))) unsigned*)(l),
                                   16, 0, 0);
}
#define S_BARRIER() __builtin_amdgcn_s_barrier()
#define LGKM0() asm volatile("s_waitcnt lgkmcnt(0)" ::: "memory")
#define MEMORD() asm volatile("" ::: "memory")
template <int N> DEVINL void vmwaitc() {
  asm volatile("s_waitcnt vmcnt(%0)" :: "i"(N) : "memory");
}
// bijective XCD swizzle (n % 8 == 0): consecutive output slots cluster per XCD
DEVINL int xswz(int p, int n) { return (p & 7) * (n >> 3) + (p >> 3); }

// ======== 256(M) x (NF*64... see below)(N) tile, BK=32, RING-slot LDS ring ========
// 512 threads = 8 waves (2M x 4N); wave tile 128 x (NF*16).  N-tile = 4*NF*16.
// Slot layout (shorts): A [256][32] = 8192, then B [BU*128][32] = BU*4096.
// Per K-tile: 2 phases x {ds_reads | stage issues | barrier | lgkmcnt(0) | MFMA | barrier}.
// Stage of tile kt+RING-1 -> slot (kt+RING-1)%RING == (kt-1)%RING, vacated at end of
// kt-1 (reads drained via lgkmcnt(0) before that tile's last MFMA+barrier) -> no WAR.
// vmcnt((RING-2)*U) once per K-tile (U = loads/K-tile = 2+BU); never 0 mid-loop.
// Bank swizzle: storage chunk = logical chunk ^ ((row>>1)&3), applied as inverse-swizzled
// GLOBAL source + swizzled ds_read (both-sides rule). Verified 0 conflicts (r2/r3).
template <int BU, int NF, int RING>
DEVINL void gemm_core(const short* __restrict__ Ag, const short* __restrict__ Bg,
                      int lda, int ldb, int m0, int n0, int nkt,
                      short* lds, f32x4 (&acc)[8][NF]) {
  constexpr int U = 2 + BU;              // loads per K-tile
  constexpr int SLOT = 8192 + BU * 4096; // shorts per ring slot
  constexpr int WS = (RING - 2) * U;     // steady-state vmcnt
  const int tid = threadIdx.x;
  const int w = tid >> 6, l = tid & 63;
  const int wm = w >> 2, wn = w & 3;
  const int lr = l & 15, lg = l >> 4;
  const int stg_row = w * 16 + (l >> 2);
  const int stg_col = (((l & 3) ^ ((l >> 3) & 3)) << 3);   // inverse-swizzled source col
  const int ck = ((lg ^ ((lr >> 1) & 3)) << 3);            // swizzled read chunk
  const int aro = (wm * 128 + lr) * 32 + ck;               // + qh*2048 + mf*512
  const int bro = 8192 + (wn * (NF * 16) + lr) * 32 + ck;  // + nf*512
  const int dW = w * 512;                                  // wave-uniform LDS dest

  // ---- prologue: stage K-tiles 0..RING-2; wait tile0; barrier ----
#pragma unroll
  for (int t = 0; t < RING - 1; ++t) {
    short* S = lds + t * SLOT;
    gload_lds16(Ag + (size_t)(m0 + stg_row) * lda + t * 32 + stg_col, S + dW);
    gload_lds16(Ag + (size_t)(m0 + 128 + stg_row) * lda + t * 32 + stg_col, S + 4096 + dW);
#pragma unroll
    for (int u = 0; u < BU; ++u)
      gload_lds16(Bg + (size_t)(n0 + u * 128 + stg_row) * ldb + t * 32 + stg_col,
                  S + 8192 + u * 4096 + dW);
  }
  vmwaitc<WS>(); S_BARRIER(); MEMORD();

  int cur = 0, stg = RING - 1;
  bfv8 a[4], b[NF];
#pragma unroll 1
  for (int kt = 0; kt < nkt; ++kt) {
    const short* Sc = lds + cur * SLOT;
    short* Ss = lds + stg * SLOT;
    const int ks = kt + (RING - 1);
    // ---------- phase q0: rows [0,64) of wave tile ----------
#pragma unroll
    for (int mf = 0; mf < 4; ++mf) a[mf] = *(const bfv8*)(Sc + aro + mf * 512);
#pragma unroll
    for (int nf = 0; nf < NF; ++nf) b[nf] = *(const bfv8*)(Sc + bro + nf * 512);
    if (ks < nkt) {
      gload_lds16(Ag + (size_t)(m0 + stg_row) * lda + ks * 32 + stg_col, Ss + dW);
      gload_lds16(Ag + (size_t)(m0 + 128 + stg_row) * lda + ks * 32 + stg_col, Ss + 4096 + dW);
    }
    S_BARRIER(); LGKM0();
    __builtin_amdgcn_s_setprio(1);
#pragma unroll
    for (int mf = 0; mf < 4; ++mf)
#pragma unroll
      for (int nf = 0; nf < NF; ++nf)
        acc[mf][nf] = __builtin_amdgcn_mfma_f32_16x16x32_bf16(a[mf], b[nf], acc[mf][nf], 0, 0, 0);
    __builtin_amdgcn_s_setprio(0);
    S_BARRIER(); MEMORD();
    // ---------- phase q1: rows [64,128) of wave tile ----------
#pragma unroll
    for (int mf = 0; mf < 4; ++mf) a[mf] = *(const bfv8*)(Sc + aro + 2048 + mf * 512);
    if (ks < nkt) {
#pragma unroll
      for (int u = 0; u < BU; ++u)
        gload_lds16(Bg + (size_t)(n0 + u * 128 + stg_row) * ldb + ks * 32 + stg_col,
                    Ss + 8192 + u * 4096 + dW);
    }
    if (kt + 1 < nkt) {
      if (ks < nkt) vmwaitc<WS>();
      else if (kt + 2 < nkt) vmwaitc<U>();   // ring-4 tail only
      else vmwaitc<0>();                     // last prefetched tile
    }
    S_BARRIER(); LGKM0();
    __builtin_amdgcn_s_setprio(1);
#pragma unroll
    for (int mf = 0; mf < 4; ++mf)
#pragma unroll
      for (int nf = 0; nf < NF; ++nf)
        acc[4 + mf][nf] = __builtin_amdgcn_mfma_f32_16x16x32_bf16(a[mf], b[nf], acc[4 + mf][nf], 0, 0, 0);
    __builtin_amdgcn_s_setprio(0);
    S_BARRIER(); MEMORD();
    cur = (cur + 1 == RING) ? 0 : cur + 1;
    stg = (stg + 1 == RING) ? 0 : stg + 1;
  }
}

// ============ prep: cast fp32->bf16 (Q,V) fused with W transpose+cast ============
__global__ __launch_bounds__(256) void prep_kernel(
    const float* __restrict__ q, const float* __restrict__ v,
    const float* __restrict__ Wq, const float* __restrict__ Wk, const float* __restrict__ Wv,
    short* __restrict__ Qc, short* __restrict__ Vc,
    short* __restrict__ WTq, short* __restrict__ WTk, short* __restrict__ WTv) {
  __shared__ float tile[64][65];
  const int bx = blockIdx.x;
  if (bx < 8192) {
    const float* src = (bx < 4096) ? q : v;
    short* dst = (bx < 4096) ? Qc : Vc;
    const size_t i = ((size_t)(bx & 4095) * 256 + threadIdx.x) * 8;
    f32x4 x0 = *(const f32x4*)(src + i);
    f32x4 x1 = *(const f32x4*)(src + i + 4);
    s16x8 o;
#pragma unroll
    for (int j = 0; j < 4; ++j) { o[j] = f2bf(x0[j]); o[4 + j] = f2bf(x1[j]); }
    *(s16x8*)(dst + i) = o;
  } else {
    const int z = (bx - 8192) >> 8, xx = (bx - 8192) & 255;
    const float* W = (z == 0) ? Wq : (z == 1) ? Wk : Wv;
    short* WT = (z == 0) ? WTq : (z == 1) ? WTk : WTv;
    const int k0 = (xx & 15) << 6, n0 = (xx >> 4) << 6;
    const int c = threadIdx.x & 63, r0 = threadIdx.x >> 6;
#pragma unroll
    for (int i = 0; i < 16; ++i) {
      int r = (i << 2) + r0;
      tile[r][c] = W[(size_t)(k0 + r) * 1024 + n0 + c];
    }
    __syncthreads();
#pragma unroll
    for (int i = 0; i < 16; ++i) {
      int a = (i << 2) + r0;
      WT[(size_t)(n0 + a) * 1024 + k0 + c] = f2bf(tile[c][a]);
    }
  }
}

// ==== Q+K projections: tile 256x128, grid 512 (2 sel x 32 bm x 8 bn), ring-3, 2 blk/CU ====
__global__ __launch_bounds__(512, 4) void qkproj_kernel(
    const short* __restrict__ Qc, const short* __restrict__ Vc,
    const short* __restrict__ WTq, const short* __restrict__ WTk,
    const float* __restrict__ bq, const float* __restrict__ bk,
    short* __restrict__ Qb, short* __restrict__ Kb) {
  __shared__ short lds[36864];  // 72 KB
  const int o = xswz(blockIdx.x, 512);
  const int sel = o >> 8, r = o & 255;
  const int bm = r >> 3, bn = r & 7;          // bm:[0,32) bn:[0,8)
  const short* A = sel ? Vc : Qc;
  const short* BT = sel ? WTk : WTq;
  const float* bias = sel ? bk : bq;
  short* O = sel ? Kb : Qb;
  const int m0 = bm * 256, n0 = bn * 128;
  f32x4 acc[8][2];
#pragma unroll
  for (int i = 0; i < 8; ++i)
#pragma unroll
    for (int j = 0; j < 2; ++j) acc[i][j] = (f32x4){0.f, 0.f, 0.f, 0.f};
  gemm_core<1, 2, 3>(A, BT, 1024, 1024, m0, n0, 32, lds, acc);
  const int tid = threadIdx.x;
  const int w = tid >> 6, l = tid & 63;
  const int wm = w >> 2, wn = w & 3, lr = l & 15, lg = l >> 4;
#pragma unroll
  for (int i = 0; i < 8; ++i) {
    const int row0 = m0 + wm * 128 + (i >> 2) * 64 + (i & 3) * 16 + lg * 4;
#pragma unroll
    for (int nf = 0; nf < 2; ++nf) {
      const int col = n0 + wn * 32 + nf * 16 + lr;  // <= n0+127
      const float bb = bias[col];
#pragma unroll
      for (int j = 0; j < 4; ++j)
        O[(size_t)(row0 + j) * 1024 + col] = f2bf(acc[i][nf][j] + bb);
    }
  }
}

// ==== V projection -> VT[b][u][t]: tile 256x128, grid 256 (32 bm x 8 bn), ring-3 ====
__global__ __launch_bounds__(512, 2) void vproj_kernel(
    const short* __restrict__ Vc, const short* __restrict__ WTv,
    const float* __restrict__ bv, short* __restrict__ VT) {
  __shared__ short lds[36864];  // 72 KB: ring 3 x 12288; reused as 128x264 transpose buf
  const int o = xswz(blockIdx.x, 256);
  const int bm = o >> 3, bn = o & 7;          // bm:[0,32) bn:[0,8)
  const int m0 = bm * 256, n0 = bn * 128;     // m = t rows, n = u cols
  f32x4 acc[8][2];
#pragma unroll
  for (int i = 0; i < 8; ++i)
#pragma unroll
    for (int j = 0; j < 2; ++j) acc[i][j] = (f32x4){0.f, 0.f, 0.f, 0.f};
  gemm_core<1, 2, 3>(Vc, WTv, 1024, 1024, m0, n0, 32, lds, acc);
  const int tid = threadIdx.x;
  const int w = tid >> 6, l = tid & 63;
  const int wm = w >> 2, wn = w & 3, lr = l & 15, lg = l >> 4;
  __syncthreads();
  short* lt = lds;  // [u_local 0..127][t_local 0..255], stride 264
#pragma unroll
  for (int i = 0; i < 8; ++i) {
    const int tl = wm * 128 + (i >> 2) * 64 + (i & 3) * 16 + lg * 4;
#pragma unroll
    for (int nf = 0; nf < 2; ++nf) {
      const int ul = wn * 32 + nf * 16 + lr;
      const float bb = bv[n0 + ul];
      s16x4 pk;
#pragma unroll
      for (int j = 0; j < 4; ++j) pk[j] = f2bf(acc[i][nf][j] + bb);
      *(s16x4*)&lt[ul * 264 + tl] = pk;
    }
  }
  __syncthreads();
  const int b = m0 >> 11, t0 = m0 & 2047;
#pragma unroll
  for (int it = 0; it < 8; ++it) {
    const int cid = it * 512 + tid;
    const int u = cid >> 5, tc = cid & 31;
    s16x8 v8 = *(const s16x8*)&lt[u * 264 + tc * 8];
    *(s16x8*)(VT + ((size_t)b * 1024 + n0 + u) * 2048 + t0 + tc * 8) = v8;
  }
}

// ==== QK^T: scores=(Q.K)/32; tile 256x128, grid 512 (4 bt x 8 bm x 16 bn), 2 blk/CU ====
__global__ __launch_bounds__(512, 4) void qkt_kernel(const short* __restrict__ Qb,
                                                     const short* __restrict__ Kb,
                                                     short* __restrict__ Sb) {
  __shared__ short lds[36864];  // 72 KB
  const int o = xswz(blockIdx.x, 512);
  const int bt = o >> 7, r = o & 127;         // bt:[0,4)
  const int bm = r >> 4, bn = r & 15;         // bm:[0,8) bn:[0,16)
  const short* A = Qb + (size_t)bt * 2097152;
  const short* B = Kb + (size_t)bt * 2097152;
  short* O = Sb + (size_t)bt * 4194304;
  const int m0 = bm * 256, n0 = bn * 128;
  f32x4 acc[8][2];
#pragma unroll
  for (int i = 0; i < 8; ++i)
#pragma unroll
    for (int j = 0; j < 2; ++j) acc[i][j] = (f32x4){0.f, 0.f, 0.f, 0.f};
  gemm_core<1, 2, 3>(A, B, 1024, 1024, m0, n0, 32, lds, acc);
  const int tid = threadIdx.x;
  const int w = tid >> 6, l = tid & 63;
  const int wm = w >> 2, wn = w & 3, lr = l & 15, lg = l >> 4;
#pragma unroll
  for (int i = 0; i < 8; ++i) {
    const int row0 = m0 + wm * 128 + (i >> 2) * 64 + (i & 3) * 16 + lg * 4;  // <= 2047
#pragma unroll
    for (int nf = 0; nf < 2; ++nf) {
      const int col = n0 + wn * 32 + nf * 16 + lr;  // <= 2047
#pragma unroll
      for (int j = 0; j < 4; ++j)
        O[(size_t)(row0 + j) * 2048 + col] = f2bf(acc[i][nf][j] * 0.03125f);
    }
  }
}

// ==== PV: out = P @ V (V via VT), fp32; tile 256x128, grid 256 (4 bt x 8 bm x 8 bn) ====
__global__ __launch_bounds__(512, 2) void pv_kernel(const short* __restrict__ Sb,
                                                    const short* __restrict__ VT,
                                                    float* __restrict__ Out) {
  __shared__ short lds[36864];  // 72 KB
  const int o = xswz(blockIdx.x, 256);
  const int bt = o >> 6, r = o & 63;          // bt:[0,4)  (FIXED: grid is 256)
  const int bm = r >> 3, bn = r & 7;          // bm:[0,8) bn:[0,8)
  const short* A = Sb + (size_t)bt * 4194304;
  const short* B = VT + (size_t)bt * 2097152;
  float* O = Out + (size_t)bt * 2097152;
  const int m0 = bm * 256, n0 = bn * 128;
  f32x4 acc[8][2];
#pragma unroll
  for (int i = 0; i < 8; ++i)
#pragma unroll
    for (int j = 0; j < 2; ++j) acc[i][j] = (f32x4){0.f, 0.f, 0.f, 0.f};
  gemm_core<1, 2, 3>(A, B, 2048, 2048, m0, n0, 64, lds, acc);
  const int l = threadIdx.x & 63, w = threadIdx.x >> 6;
  const int wm = w >> 2, wn = w & 3, lr = l & 15, lg = l >> 4;
#pragma unroll
  for (int i = 0; i < 8; ++i) {
    const int row0 = m0 + wm * 128 + (i >> 2) * 64 + (i & 3) * 16 + lg * 4;  // <= 2047
#pragma unroll
    for (int nf = 0; nf < 2; ++nf) {
      const int col = n0 + wn * 32 + nf * 16 + lr;  // <= 1023
#pragma unroll
      for (int j = 0; j < 4; ++j)
        O[(size_t)(row0 + j) * 1024 + col] = acc[i][nf][j];
    }
  }
}

// ============ Row softmax, in-place on bf16 scores [B*S rows][2048] ============
__global__ __launch_bounds__(256) void softmax_kernel(short* __restrict__ Sb) {
  const size_t row = blockIdx.x;
  short* p = Sb + row * 2048;
  const int tid = threadIdx.x;
  const int w = tid >> 6, l = tid & 63;
  s16x8 v = *(const s16x8*)(p + tid * 8);
  float f[8];
#pragma unroll
  for (int j = 0; j < 8; ++j) f[j] = bf2f(v[j]);
  float m = f[0];
#pragma unroll
  for (int j = 1; j < 8; ++j) m = fmaxf(m, f[j]);
#pragma unroll
  for (int o = 32; o > 0; o >>= 1) m = fmaxf(m, __shfl_xor(m, o, 64));
  __shared__ float redm[4], reds[4];
  if (l == 0) redm[w] = m;
  __syncthreads();
  m = fmaxf(fmaxf(redm[0], redm[1]), fmaxf(redm[2], redm[3]));
  float s = 0.f;
#pragma unroll
  for (int j = 0; j < 8; ++j) { f[j] = __expf(f[j] - m); s += f[j]; }
#pragma unroll
  for (int o = 32; o > 0; o >>= 1) s += __shfl_xor(s, o, 64);
  if (l == 0) reds[w] = s;
  __syncthreads();
  s = reds[0] + reds[1] + reds[2] + reds[3];
  const float inv = 1.f / s;
  s16x8 o8;
#pragma unroll
  for (int j = 0; j < 8; ++j) o8[j] = f2bf(f[j] * inv);
  *(s16x8*)(p + tid * 8) = o8;
}

// ============ launch ============
extern "C" void kernel_launch(void* const* d_in, const int* in_sizes, int n_in,
                              void* d_out, int out_size, void* d_ws, size_t ws_size,
                              hipStream_t stream) {
  const float* query = (const float*)d_in[0];
  const float* value = (const float*)d_in[1];
  const float* Wq = (const float*)d_in[2];
  const float* bq = (const float*)d_in[3];
  const float* Wk = (const float*)d_in[4];
  const float* bk = (const float*)d_in[5];
  const float* Wv = (const float*)d_in[6];
  const float* bv = (const float*)d_in[7];

  // Workspace layout (86 MB total):
  //  0: WTq(2M) 2M: WTk(2M) 4M: WTv(2M)
  //  6M: region X (32MB): Qc@6M(16M), Vc@22M(16M) [projection inputs];
  //      later reused as Sb@6M(32MB) [scores/P] -- lifetimes disjoint (stream-ordered)
  //  38M: Qb(16M)  54M: Kb(16M)  70M: VT(16M)
  char* ws = (char*)d_ws;
  short* WTq = (short*)(ws);
  short* WTk = (short*)(ws + ((size_t)2 << 20));
  short* WTv = (short*)(ws + ((size_t)4 << 20));
  short* Qc  = (short*)(ws + ((size_t)6 << 20));
  short* Vc  = (short*)(ws + ((size_t)22 << 20));
  short* Sb  = (short*)(ws + ((size_t)6 << 20));
  short* Qb  = (short*)(ws + ((size_t)38 << 20));
  short* Kb  = (short*)(ws + ((size_t)54 << 20));
  short* VT  = (short*)(ws + ((size_t)70 << 20));

  prep_kernel<<<dim3(8960), 256, 0, stream>>>(query, value, Wq, Wk, Wv, Qc, Vc, WTq, WTk, WTv);

  qkproj_kernel<<<dim3(512), 512, 0, stream>>>(Qc, Vc, WTq, WTk, bq, bk, Qb, Kb);
  vproj_kernel<<<dim3(256), 512, 0, stream>>>(Vc, WTv, bv, VT);

  // scores[b][s][t] = (Q.K)/32
  qkt_kernel<<<dim3(512), 512, 0, stream>>>(Qb, Kb, Sb);

  softmax_kernel<<<dim3(8192), 256, 0, stream>>>(Sb);

  // out[b][s][u] = P @ V
  pv_kernel<<<dim3(256), 512, 0, stream>>>(Sb, VT, (float*)d_out);
}

// Round 7
// 190.232 us; speedup vs baseline: 2.3266x; 1.0145x over previous
//
#include <hip/hip_runtime.h>
#include <hip/hip_bf16.h>
#include <stdint.h>

#define DEVINL __device__ __forceinline__

typedef __attribute__((ext_vector_type(4))) float f32x4;
typedef __attribute__((ext_vector_type(8))) __bf16 bfv8;
typedef __attribute__((ext_vector_type(8))) short s16x8;
typedef __attribute__((ext_vector_type(4))) short s16x4;

// ---- helpers ----
DEVINL short f2bf(float f) {  // fp32 -> bf16 bits, RTNE
  union { float f; unsigned u; } v; v.f = f;
  unsigned r = v.u + 0x7FFFu + ((v.u >> 16) & 1u);
  return (short)(r >> 16);
}
DEVINL float bf2f(short h) {
  union { unsigned u; float f; } v; v.u = ((unsigned)(unsigned short)h) << 16;
  return v.f;
}
DEVINL void gload_lds16(const void* g, void* l) {
  // 16B direct global->LDS. LDS dest = wave-uniform base + lane*16.
  __builtin_amdgcn_global_load_lds((__attribute__((address_space(1))) unsigned*)(g),
                                   (__attribute__((address_space(3))) unsigned*)(l),
                                   16, 0, 0);
}
#define S_BARRIER() __builtin_amdgcn_s_barrier()
#define MEMORD() asm volatile("" ::: "memory")
template <int N> DEVINL void vmwaitc() {
  asm volatile("s_waitcnt vmcnt(%0)" :: "i"(N) : "memory");
}
// bijective XCD swizzle (n % 8 == 0): consecutive output slots cluster per XCD
DEVINL int xswz(int p, int n) { return (p & 7) * (n >> 3) + (p >> 3); }

// ======== 256(M) x (4*NF*16)(N) tile, BK=32, RING-slot LDS ring, READ-AHEAD core ========
// 512 threads = 8 waves (2M x 4N); wave tile 128 x (NF*16).
// Slot layout (shorts): A [256][32] = 8192, then B [BU*128][32] = BU*4096.
// READ-AHEAD pipeline: each phase issues ds_reads for the NEXT MFMA cluster, then runs
// MFMA on regs loaded the previous phase (reads overlap MFMA; compiler handles lgkm deps).
// Phase layout per K-tile (2 phases, 2 barriers — was 4):
//   q0: stage A(kt+2) | read aB=A1(kt)            | MFMA(aA,bA) | vmcnt(2) | BAR
//   q1: stage B(kt+2) | read aA=A0(kt+1),bB=B(kt+1)| MFMA(aB,bA) |           BAR
// Hazards: stage of kt+2 -> slot (kt-1)%RING whose last reads ended >=2 barriers earlier
// (no WAR); vmcnt(2) leaves only the 2 newest A-loads -> tile kt+1 fully landed, and the
// following BAR makes all waves' loads globally visible before any wave reads kt+1.
// Bank swizzle: storage chunk = logical chunk ^ ((row>>1)&3), inverse-swizzled GLOBAL
// source + swizzled ds_read (both-sides rule). Verified 0 conflicts (r2/r3/r6).
template <int BU, int NF, int RING>
DEVINL void gemm_core(const short* __restrict__ Ag, const short* __restrict__ Bg,
                      int lda, int ldb, int m0, int n0, int nkt,
                      short* lds, f32x4 (&acc)[8][NF]) {
  constexpr int U = 2 + BU;              // loads per K-tile
  constexpr int SLOT = 8192 + BU * 4096; // shorts per ring slot
  const int tid = threadIdx.x;
  const int w = tid >> 6, l = tid & 63;
  const int wm = w >> 2, wn = w & 3;
  const int lr = l & 15, lg = l >> 4;
  const int stg_row = w * 16 + (l >> 2);
  const int stg_col = (((l & 3) ^ ((l >> 3) & 3)) << 3);   // inverse-swizzled source col
  const int ck = ((lg ^ ((lr >> 1) & 3)) << 3);            // swizzled read chunk
  const int aro = (wm * 128 + lr) * 32 + ck;               // + 2048 for A1-half, + mf*512
  const int bro = 8192 + (wn * (NF * 16) + lr) * 32 + ck;  // + nf*512
  const int dW = w * 512;                                  // wave-uniform LDS dest

#define STAGE_A(t) { short* S_ = lds + ((t) % RING) * SLOT;                                \
    gload_lds16(Ag + (size_t)(m0 + stg_row) * lda + (t) * 32 + stg_col, S_ + dW);          \
    gload_lds16(Ag + (size_t)(m0 + 128 + stg_row) * lda + (t) * 32 + stg_col,              \
                S_ + 4096 + dW); }
#define STAGE_B(t) { short* S_ = lds + ((t) % RING) * SLOT;                                \
    _Pragma("unroll")                                                                      \
    for (int u_ = 0; u_ < BU; ++u_)                                                        \
      gload_lds16(Bg + (size_t)(n0 + u_ * 128 + stg_row) * ldb + (t) * 32 + stg_col,       \
                  S_ + 8192 + u_ * 4096 + dW); }

  // ---- prologue: stage tiles 0..RING-2; wait tile0; barrier; preload tile0 regs ----
#pragma unroll
  for (int t = 0; t < RING - 1; ++t) { STAGE_A(t); STAGE_B(t); }
  vmwaitc<(RING - 2) * U>(); S_BARRIER(); MEMORD();

  bfv8 aA[4], aB[4], bA[NF], bB[NF];
  {
    const short* Sp = lds;  // slot 0
#pragma unroll
    for (int mf = 0; mf < 4; ++mf) aA[mf] = *(const bfv8*)(Sp + aro + mf * 512);
#pragma unroll
    for (int nf = 0; nf < NF; ++nf) bA[nf] = *(const bfv8*)(Sp + bro + nf * 512);
  }

#pragma unroll 1
  for (int kt = 0; kt < nkt; kt += 2) {  // nkt even (32/64): 2 K-tiles per iteration
    const short* S0 = lds + (kt % RING) * SLOT;
    const short* S1 = lds + ((kt + 1) % RING) * SLOT;
    const short* S2 = lds + ((kt + 2) % RING) * SLOT;
    // ---- tile kt, q0 ----
    if (kt + 2 < nkt) STAGE_A(kt + 2);
#pragma unroll
    for (int mf = 0; mf < 4; ++mf) aB[mf] = *(const bfv8*)(S0 + aro + 2048 + mf * 512);
#pragma unroll
    for (int mf = 0; mf < 4; ++mf)
#pragma unroll
      for (int nf = 0; nf < NF; ++nf)
        acc[mf][nf] = __builtin_amdgcn_mfma_f32_16x16x32_bf16(aA[mf], bA[nf], acc[mf][nf], 0, 0, 0);
    if (kt + 2 < nkt) vmwaitc<2>(); else vmwaitc<0>();
    S_BARRIER(); MEMORD();
    // ---- tile kt, q1 ----
    if (kt + 2 < nkt) STAGE_B(kt + 2);
#pragma unroll
    for (int mf = 0; mf < 4; ++mf) aA[mf] = *(const bfv8*)(S1 + aro + mf * 512);
#pragma unroll
    for (int nf = 0; nf < NF; ++nf) bB[nf] = *(const bfv8*)(S1 + bro + nf * 512);
#pragma unroll
    for (int mf = 0; mf < 4; ++mf)
#pragma unroll
      for (int nf = 0; nf < NF; ++nf)
        acc[4 + mf][nf] = __builtin_amdgcn_mfma_f32_16x16x32_bf16(aB[mf], bA[nf], acc[4 + mf][nf], 0, 0, 0);
    S_BARRIER(); MEMORD();
    // ---- tile kt+1, q0 ----
    if (kt + 3 < nkt) STAGE_A(kt + 3);
#pragma unroll
    for (int mf = 0; mf < 4; ++mf) aB[mf] = *(const bfv8*)(S1 + aro + 2048 + mf * 512);
#pragma unroll
    for (int mf = 0; mf < 4; ++mf)
#pragma unroll
      for (int nf = 0; nf < NF; ++nf)
        acc[mf][nf] = __builtin_amdgcn_mfma_f32_16x16x32_bf16(aA[mf], bB[nf], acc[mf][nf], 0, 0, 0);
    if (kt + 3 < nkt) vmwaitc<2>(); else vmwaitc<0>();
    S_BARRIER(); MEMORD();
    // ---- tile kt+1, q1 ----
    if (kt + 3 < nkt) STAGE_B(kt + 3);
    if (kt + 2 < nkt) {
#pragma unroll
      for (int mf = 0; mf < 4; ++mf) aA[mf] = *(const bfv8*)(S2 + aro + mf * 512);
#pragma unroll
      for (int nf = 0; nf < NF; ++nf) bA[nf] = *(const bfv8*)(S2 + bro + nf * 512);
    }
#pragma unroll
    for (int mf = 0; mf < 4; ++mf)
#pragma unroll
      for (int nf = 0; nf < NF; ++nf)
        acc[4 + mf][nf] = __builtin_amdgcn_mfma_f32_16x16x32_bf16(aB[mf], bB[nf], acc[4 + mf][nf], 0, 0, 0);
    S_BARRIER(); MEMORD();
  }
#undef STAGE_A
#undef STAGE_B
}

// ============ prep: cast fp32->bf16 (Q,V) fused with W transpose+cast ============
__global__ __launch_bounds__(256) void prep_kernel(
    const float* __restrict__ q, const float* __restrict__ v,
    const float* __restrict__ Wq, const float* __restrict__ Wk, const float* __restrict__ Wv,
    short* __restrict__ Qc, short* __restrict__ Vc,
    short* __restrict__ WTq, short* __restrict__ WTk, short* __restrict__ WTv) {
  __shared__ float tile[64][65];
  const int bx = blockIdx.x;
  if (bx < 8192) {
    const float* src = (bx < 4096) ? q : v;
    short* dst = (bx < 4096) ? Qc : Vc;
    const size_t i = ((size_t)(bx & 4095) * 256 + threadIdx.x) * 8;
    f32x4 x0 = *(const f32x4*)(src + i);
    f32x4 x1 = *(const f32x4*)(src + i + 4);
    s16x8 o;
#pragma unroll
    for (int j = 0; j < 4; ++j) { o[j] = f2bf(x0[j]); o[4 + j] = f2bf(x1[j]); }
    *(s16x8*)(dst + i) = o;
  } else {
    const int z = (bx - 8192) >> 8, xx = (bx - 8192) & 255;
    const float* W = (z == 0) ? Wq : (z == 1) ? Wk : Wv;
    short* WT = (z == 0) ? WTq : (z == 1) ? WTk : WTv;
    const int k0 = (xx & 15) << 6, n0 = (xx >> 4) << 6;
    const int c = threadIdx.x & 63, r0 = threadIdx.x >> 6;
#pragma unroll
    for (int i = 0; i < 16; ++i) {
      int r = (i << 2) + r0;
      tile[r][c] = W[(size_t)(k0 + r) * 1024 + n0 + c];
    }
    __syncthreads();
#pragma unroll
    for (int i = 0; i < 16; ++i) {
      int a = (i << 2) + r0;
      WT[(size_t)(n0 + a) * 1024 + k0 + c] = f2bf(tile[c][a]);
    }
  }
}

// ==== Q+K projections: tile 256x128, grid 512 (2 sel x 32 bm x 8 bn), ring-3, 2 blk/CU ====
__global__ __launch_bounds__(512, 4) void qkproj_kernel(
    const short* __restrict__ Qc, const short* __restrict__ Vc,
    const short* __restrict__ WTq, const short* __restrict__ WTk,
    const float* __restrict__ bq, const float* __restrict__ bk,
    short* __restrict__ Qb, short* __restrict__ Kb) {
  __shared__ short lds[36864];  // 72 KB
  const int o = xswz(blockIdx.x, 512);
  const int sel = o >> 8, r = o & 255;
  const int bm = r >> 3, bn = r & 7;          // bm:[0,32) bn:[0,8)
  const short* A = sel ? Vc : Qc;
  const short* BT = sel ? WTk : WTq;
  const float* bias = sel ? bk : bq;
  short* O = sel ? Kb : Qb;
  const int m0 = bm * 256, n0 = bn * 128;
  f32x4 acc[8][2];
#pragma unroll
  for (int i = 0; i < 8; ++i)
#pragma unroll
    for (int j = 0; j < 2; ++j) acc[i][j] = (f32x4){0.f, 0.f, 0.f, 0.f};
  gemm_core<1, 2, 3>(A, BT, 1024, 1024, m0, n0, 32, lds, acc);
  const int tid = threadIdx.x;
  const int w = tid >> 6, l = tid & 63;
  const int wm = w >> 2, wn = w & 3, lr = l & 15, lg = l >> 4;
#pragma unroll
  for (int i = 0; i < 8; ++i) {
    const int row0 = m0 + wm * 128 + (i >> 2) * 64 + (i & 3) * 16 + lg * 4;
#pragma unroll
    for (int nf = 0; nf < 2; ++nf) {
      const int col = n0 + wn * 32 + nf * 16 + lr;  // <= n0+127
      const float bb = bias[col];
#pragma unroll
      for (int j = 0; j < 4; ++j)
        O[(size_t)(row0 + j) * 1024 + col] = f2bf(acc[i][nf][j] + bb);
    }
  }
}

// ==== V projection -> VT[b][u][t]: tile 256x128, grid 256 (32 bm x 8 bn), ring-3 ====
__global__ __launch_bounds__(512, 2) void vproj_kernel(
    const short* __restrict__ Vc, const short* __restrict__ WTv,
    const float* __restrict__ bv, short* __restrict__ VT) {
  __shared__ short lds[36864];  // 72 KB: ring 3 x 12288; reused as 128x264 transpose buf
  const int o = xswz(blockIdx.x, 256);
  const int bm = o >> 3, bn = o & 7;          // bm:[0,32) bn:[0,8)
  const int m0 = bm * 256, n0 = bn * 128;     // m = t rows, n = u cols
  f32x4 acc[8][2];
#pragma unroll
  for (int i = 0; i < 8; ++i)
#pragma unroll
    for (int j = 0; j < 2; ++j) acc[i][j] = (f32x4){0.f, 0.f, 0.f, 0.f};
  gemm_core<1, 2, 3>(Vc, WTv, 1024, 1024, m0, n0, 32, lds, acc);
  const int tid = threadIdx.x;
  const int w = tid >> 6, l = tid & 63;
  const int wm = w >> 2, wn = w & 3, lr = l & 15, lg = l >> 4;
  __syncthreads();
  short* lt = lds;  // [u_local 0..127][t_local 0..255], stride 264
#pragma unroll
  for (int i = 0; i < 8; ++i) {
    const int tl = wm * 128 + (i >> 2) * 64 + (i & 3) * 16 + lg * 4;
#pragma unroll
    for (int nf = 0; nf < 2; ++nf) {
      const int ul = wn * 32 + nf * 16 + lr;
      const float bb = bv[n0 + ul];
      s16x4 pk;
#pragma unroll
      for (int j = 0; j < 4; ++j) pk[j] = f2bf(acc[i][nf][j] + bb);
      *(s16x4*)&lt[ul * 264 + tl] = pk;
    }
  }
  __syncthreads();
  const int b = m0 >> 11, t0 = m0 & 2047;
#pragma unroll
  for (int it = 0; it < 8; ++it) {
    const int cid = it * 512 + tid;
    const int u = cid >> 5, tc = cid & 31;
    s16x8 v8 = *(const s16x8*)&lt[u * 264 + tc * 8];
    *(s16x8*)(VT + ((size_t)b * 1024 + n0 + u) * 2048 + t0 + tc * 8) = v8;
  }
}

// ==== QK^T: scores=(Q.K)/32; tile 256x128, grid 512 (4 bt x 8 bm x 16 bn), 2 blk/CU ====
__global__ __launch_bounds__(512, 4) void qkt_kernel(const short* __restrict__ Qb,
                                                     const short* __restrict__ Kb,
                                                     short* __restrict__ Sb) {
  __shared__ short lds[36864];  // 72 KB
  const int o = xswz(blockIdx.x, 512);
  const int bt = o >> 7, r = o & 127;         // bt:[0,4)
  const int bm = r >> 4, bn = r & 15;         // bm:[0,8) bn:[0,16)
  const short* A = Qb + (size_t)bt * 2097152;
  const short* B = Kb + (size_t)bt * 2097152;
  short* O = Sb + (size_t)bt * 4194304;
  const int m0 = bm * 256, n0 = bn * 128;
  f32x4 acc[8][2];
#pragma unroll
  for (int i = 0; i < 8; ++i)
#pragma unroll
    for (int j = 0; j < 2; ++j) acc[i][j] = (f32x4){0.f, 0.f, 0.f, 0.f};
  gemm_core<1, 2, 3>(A, B, 1024, 1024, m0, n0, 32, lds, acc);
  const int tid = threadIdx.x;
  const int w = tid >> 6, l = tid & 63;
  const int wm = w >> 2, wn = w & 3, lr = l & 15, lg = l >> 4;
#pragma unroll
  for (int i = 0; i < 8; ++i) {
    const int row0 = m0 + wm * 128 + (i >> 2) * 64 + (i & 3) * 16 + lg * 4;  // <= 2047
#pragma unroll
    for (int nf = 0; nf < 2; ++nf) {
      const int col = n0 + wn * 32 + nf * 16 + lr;  // <= 2047
#pragma unroll
      for (int j = 0; j < 4; ++j)
        O[(size_t)(row0 + j) * 2048 + col] = f2bf(acc[i][nf][j] * 0.03125f);
    }
  }
}

// ==== PV: out = P @ V (V via VT), fp32; tile 256x128, grid 256 (4 bt x 8 bm x 8 bn) ====
__global__ __launch_bounds__(512, 2) void pv_kernel(const short* __restrict__ Sb,
                                                    const short* __restrict__ VT,
                                                    float* __restrict__ Out) {
  __shared__ short lds[36864];  // 72 KB
  const int o = xswz(blockIdx.x, 256);
  const int bt = o >> 6, r = o & 63;          // bt:[0,4)
  const int bm = r >> 3, bn = r & 7;          // bm:[0,8) bn:[0,8)
  const short* A = Sb + (size_t)bt * 4194304;
  const short* B = VT + (size_t)bt * 2097152;
  float* O = Out + (size_t)bt * 2097152;
  const int m0 = bm * 256, n0 = bn * 128;
  f32x4 acc[8][2];
#pragma unroll
  for (int i = 0; i < 8; ++i)
#pragma unroll
    for (int j = 0; j < 2; ++j) acc[i][j] = (f32x4){0.f, 0.f, 0.f, 0.f};
  gemm_core<1, 2, 3>(A, B, 2048, 2048, m0, n0, 64, lds, acc);
  const int l = threadIdx.x & 63, w = threadIdx.x >> 6;
  const int wm = w >> 2, wn = w & 3, lr = l & 15, lg = l >> 4;
#pragma unroll
  for (int i = 0; i < 8; ++i) {
    const int row0 = m0 + wm * 128 + (i >> 2) * 64 + (i & 3) * 16 + lg * 4;  // <= 2047
#pragma unroll
    for (int nf = 0; nf < 2; ++nf) {
      const int col = n0 + wn * 32 + nf * 16 + lr;  // <= 1023
#pragma unroll
      for (int j = 0; j < 4; ++j)
        O[(size_t)(row0 + j) * 1024 + col] = acc[i][nf][j];
    }
  }
}

// ============ Row softmax, in-place on bf16 scores [B*S rows][2048] ============
__global__ __launch_bounds__(256) void softmax_kernel(short* __restrict__ Sb) {
  const size_t row = blockIdx.x;
  short* p = Sb + row * 2048;
  const int tid = threadIdx.x;
  const int w = tid >> 6, l = tid & 63;
  s16x8 v = *(const s16x8*)(p + tid * 8);
  float f[8];
#pragma unroll
  for (int j = 0; j < 8; ++j) f[j] = bf2f(v[j]);
  float m = f[0];
#pragma unroll
  for (int j = 1; j < 8; ++j) m = fmaxf(m, f[j]);
#pragma unroll
  for (int o = 32; o > 0; o >>= 1) m = fmaxf(m, __shfl_xor(m, o, 64));
  __shared__ float redm[4], reds[4];
  if (l == 0) redm[w] = m;
  __syncthreads();
  m = fmaxf(fmaxf(redm[0], redm[1]), fmaxf(redm[2], redm[3]));
  float s = 0.f;
#pragma unroll
  for (int j = 0; j < 8; ++j) { f[j] = __expf(f[j] - m); s += f[j]; }
#pragma unroll
  for (int o = 32; o > 0; o >>= 1) s += __shfl_xor(s, o, 64);
  if (l == 0) reds[w] = s;
  __syncthreads();
  s = reds[0] + reds[1] + reds[2] + reds[3];
  const float inv = 1.f / s;
  s16x8 o8;
#pragma unroll
  for (int j = 0; j < 8; ++j) o8[j] = f2bf(f[j] * inv);
  *(s16x8*)(p + tid * 8) = o8;
}

// ============ launch ============
extern "C" void kernel_launch(void* const* d_in, const int* in_sizes, int n_in,
                              void* d_out, int out_size, void* d_ws, size_t ws_size,
                              hipStream_t stream) {
  const float* query = (const float*)d_in[0];
  const float* value = (const float*)d_in[1];
  const float* Wq = (const float*)d_in[2];
  const float* bq = (const float*)d_in[3];
  const float* Wk = (const float*)d_in[4];
  const float* bk = (const float*)d_in[5];
  const float* Wv = (const float*)d_in[6];
  const float* bv = (const float*)d_in[7];

  // Workspace layout (86 MB total):
  //  0: WTq(2M) 2M: WTk(2M) 4M: WTv(2M)
  //  6M: region X (32MB): Qc@6M(16M), Vc@22M(16M) [projection inputs];
  //      later reused as Sb@6M(32MB) [scores/P] -- lifetimes disjoint (stream-ordered)
  //  38M: Qb(16M)  54M: Kb(16M)  70M: VT(16M)
  char* ws = (char*)d_ws;
  short* WTq = (short*)(ws);
  short* WTk = (short*)(ws + ((size_t)2 << 20));
  short* WTv = (short*)(ws + ((size_t)4 << 20));
  short* Qc  = (short*)(ws + ((size_t)6 << 20));
  short* Vc  = (short*)(ws + ((size_t)22 << 20));
  short* Sb  = (short*)(ws + ((size_t)6 << 20));
  short* Qb  = (short*)(ws + ((size_t)38 << 20));
  short* Kb  = (short*)(ws + ((size_t)54 << 20));
  short* VT  = (short*)(ws + ((size_t)70 << 20));

  prep_kernel<<<dim3(8960), 256, 0, stream>>>(query, value, Wq, Wk, Wv, Qc, Vc, WTq, WTk, WTv);

  qkproj_kernel<<<dim3(512), 512, 0, stream>>>(Qc, Vc, WTq, WTk, bq, bk, Qb, Kb);
  vproj_kernel<<<dim3(256), 512, 0, stream>>>(Vc, WTv, bv, VT);

  // scores[b][s][t] = (Q.K)/32
  qkt_kernel<<<dim3(512), 512, 0, stream>>>(Qb, Kb, Sb);

  softmax_kernel<<<dim3(8192), 256, 0, stream>>>(Sb);

  // out[b][s][u] = P @ V
  pv_kernel<<<dim3(256), 512, 0, stream>>>(Sb, VT, (float*)d_out);
}